// Round 1
// 81.380 us; speedup vs baseline: 1.1029x; 1.1029x over previous
//
#include <hip/hip_runtime.h>

#define SS 304
#define HH 228
#define WW 304
#define FARV 100.0f
#define EPSV 1e-07f
#define SPLIT 8          // face-range slices (gridDim.z)
#define CH 256           // faces per slice == one staging chunk
// Each thread covers rows h and h+16 of a 32-row tile: YP(h+16) = YP(h) - 32/SS
#define DYC (-32.0f / (float)SS)

// per-vertex transform (contract off, IEEE divides — once per face, cheap)
__device__ __forceinline__ void xform_vertex(
    float u, float v, float d,
    float fx, float cx, float fy, float cy,
    float r00, float r01, float r02,
    float r10, float r11, float r12,
    float r20, float r21, float r22,
    float t0, float t1, float t2,
    float& xn, float& yn, float& z)
{
#pragma clang fp contract(off)
    float ki00 = 1.0f / fx;
    float ki02 = -(cx / fx);
    float ki11 = 1.0f / fy;
    float ki12 = -(cy / fy);
    float px = u * (float)WW;
    float py = v * (float)HH;
    float c0 = (ki00 * px + ki02) * d;
    float c1 = (ki11 * py + ki12) * d;
    float c2 = d;
    float e0 = ((r00*c0 + r01*c1) + r02*c2) + t0;
    float e1 = ((r10*c0 + r11*c1) + r12*c2) + t1;
    float e2 = ((r20*c0 + r21*c1) + r22*c2) + t2;
    z = e2;
    float zd = z + EPSV;
    float p0 = e0 / zd;
    float p1 = e1 / zd;
    float q0 = p0 * fx + cx;
    float q1 = p1 * fy + cy;
    float uu = q0 / (float)WW; uu = fminf(fmaxf(uu, 0.0f), 1.0f);
    float vv = q1 / (float)HH; vv = fminf(fmaxf(vv, 0.0f), 1.0f);
    xn = uu * (float)WW / (float)SS * 2.0f - 1.0f;
    yn = vv * (float)HH / (float)SS * 2.0f - 1.0f;
}

// ---- Kernel 1: out init + per-face vertex transform + plane precompute ----
// Per face we emit screen-space planes (sign-normalized so inside <=> >=0):
//   n0(X,Y) = A0*X + B0*Y + C0        (w0 numerator * sign(denom))
//   n1(X,Y) = A1*X + B1*Y + C1
//   n2      = |denom| - n0 - n1       (w2 numerator * sign(denom))
//   iz(X,Y) = E*X + F*Y + G           (interpolated 1/z — linear in X,Y)
__global__ __launch_bounds__(256) void prep_kernel(
    const float* __restrict__ verts,
    const int* __restrict__ faces,
    const float* __restrict__ Km,
    const float* __restrict__ Rm,
    const float* __restrict__ tm,
    float4* __restrict__ bboxArr,
    float4* __restrict__ G0arr,
    float4* __restrict__ G1arr,
    float2* __restrict__ G2arr,
    float* __restrict__ out, int M)
{
#pragma clang fp contract(off)
    int g = blockIdx.x * blockDim.x + threadIdx.x;
    if (g < HH * WW) {
        out[g] = FARV;
        out[HH * WW + g] = 0.0f;
    }
    if (g >= M) return;
    int m = g;
    int i0 = faces[3*m+0], i1 = faces[3*m+1], i2 = faces[3*m+2];
    float fx = Km[0], cx = Km[2], fy = Km[4], cy = Km[5];
    float r00 = Rm[0], r01 = Rm[1], r02 = Rm[2];
    float r10 = Rm[3], r11 = Rm[4], r12 = Rm[5];
    float r20 = Rm[6], r21 = Rm[7], r22 = Rm[8];
    float t0 = tm[0], t1 = tm[1], t2 = tm[2];

    float x0, y0, z0, x1, y1, z1, x2, y2, z2;
    xform_vertex(verts[3*i0+0], verts[3*i0+1], verts[3*i0+2], fx,cx,fy,cy,
                 r00,r01,r02,r10,r11,r12,r20,r21,r22,t0,t1,t2, x0,y0,z0);
    xform_vertex(verts[3*i1+0], verts[3*i1+1], verts[3*i1+2], fx,cx,fy,cy,
                 r00,r01,r02,r10,r11,r12,r20,r21,r22,t0,t1,t2, x1,y1,z1);
    xform_vertex(verts[3*i2+0], verts[3*i2+1], verts[3*i2+2], fx,cx,fy,cy,
                 r00,r01,r02,r10,r11,r12,r20,r21,r22,t0,t1,t2, x2,y2,z2);

    float A0 = y1 - y2;
    float B0 = x2 - x1;
    float A1 = y2 - y0;
    float B1 = x0 - x2;
    float dy02 = y0 - y2;
    float denom = A0 * B1 + B0 * dy02;
    bool ok = fabsf(denom) > 1e-10f;

    float xmin, xmax, ymin, ymax;
    if (ok) {
        xmin = fminf(x0, fminf(x1, x2)) - 1e-4f;
        xmax = fmaxf(x0, fmaxf(x1, x2)) + 1e-4f;
        ymin = fminf(y0, fminf(y1, y2)) - 1e-4f;
        ymax = fmaxf(y0, fmaxf(y1, y2)) + 1e-4f;
    } else {
        xmin = 1e30f; xmax = -1e30f; ymin = 1e30f; ymax = -1e30f;
    }
    bboxArr[m] = make_float4(xmin, xmax, ymin, ymax);

    float flip = (denom >= 0.0f) ? 1.0f : -1.0f;
    float sabs = fabsf(denom);
    float A0p = flip * A0, B0p = flip * B0;
    float C0p = -(A0p * x2 + B0p * y2);
    float A1p = flip * A1, B1p = flip * B1;
    float C1p = -(A1p * x2 + B1p * y2);
    float rz0 = 1.0f / z0, rz1 = 1.0f / z1, rz2 = 1.0f / z2;
    float D0 = rz0 / sabs, D1 = rz1 / sabs, D2 = rz2 / sabs;
    // iz = n0*D0 + n1*D1 + (sabs - n0 - n1)*D2  ->  plane E,F,G
    float d02 = D0 - D2, d12 = D1 - D2;
    float E = A0p * d02 + A1p * d12;
    float F = B0p * d02 + B1p * d12;
    float G = (C0p * d02 + C1p * d12) + sabs * D2;

    G0arr[m] = make_float4(A0p, B0p, C0p, sabs);
    G1arr[m] = make_float4(A1p, B1p, C1p, G);
    G2arr[m] = make_float2(E, F);
}

// ---- Kernel 2: rasterize (LDS-staged, face-sliced, branchless core) ----
// v2: 2 pixels per thread along Y (16x32 tile), SPLIT 16->8 / CH 128->256.
// Per face-iteration: 3 LDS broadcast reads serve TWO pixels; the second
// pixel's planes are evaluated incrementally (n += B*DYC, 1 fma each).
__global__ __launch_bounds__(256) void raster_kernel(
    const float4* __restrict__ bboxArr,
    const float4* __restrict__ G0arr,
    const float4* __restrict__ G1arr,
    const float2* __restrict__ G2arr,
    float* __restrict__ out, int M)
{
    __shared__ float4 sG0[CH];
    __shared__ float4 sG1[CH];
    __shared__ float2 sG2[CH];
    __shared__ int sCount;

    int tx = threadIdx.x, ty = threadIdx.y;
    int tid = ty * 16 + tx;
    int w  = blockIdx.x * 16 + tx;
    int h0 = blockIdx.y * 32 + ty;        // rows h0 and h0+16
    int h1 = h0 + 16;

    int wlo = blockIdx.x * 16;
    int whi = min(wlo + 15, WW - 1);
    int hlo = blockIdx.y * 32;
    int hhi = min(hlo + 31, HH - 1);
    float txlo = ((float)(2*wlo + 1 - SS)) / (float)SS;
    float txhi = ((float)(2*whi + 1 - SS)) / (float)SS;
    float tylo = ((float)(2*(SS-1-hhi) + 1 - SS)) / (float)SS;
    float tyhi = ((float)(2*(SS-1-hlo) + 1 - SS)) / (float)SS;

    if (tid == 0) sCount = 0;
    __syncthreads();

    {
        int m = blockIdx.z * CH + tid;   // M == SPLIT*CH == 2048
        if (m < M) {
            float4 rb = bboxArr[m];
            bool pass = !(rb.x > txhi || rb.y < txlo || rb.z > tyhi || rb.w < tylo);
            if (pass) {
                int i = atomicAdd(&sCount, 1);
                sG0[i] = G0arr[m];
                sG1[i] = G1arr[m];
                sG2[i] = G2arr[m];
            }
        }
    }
    __syncthreads();
    int cnt = sCount;

    {
        int irow = SS - 1 - h0;
        float XP = ((float)(2*w    + 1 - SS)) / (float)SS;
        float YP = ((float)(2*irow + 1 - SS)) / (float)SS;

        float mx0 = 0.0f;   // running max of interpolated 1/z, pixel (h0,w)
        float mx1 = 0.0f;   // pixel (h1,w)

        for (int k = 0; k < cnt; ++k) {
            float4 g0 = sG0[k];
            float4 g1 = sG1[k];
            float2 g2 = sG2[k];
            // pixel 0: full plane eval
            float n0 = fmaf(g0.x, XP, fmaf(g0.y, YP, g0.z));
            float n1 = fmaf(g1.x, XP, fmaf(g1.y, YP, g1.z));
            float iz = fmaf(g2.x, XP, fmaf(g2.y, YP, g1.w));
            float n2 = (g0.w - n0) - n1;
            float m3 = fminf(fminf(n0, n1), n2);
            mx0 = fmaxf(mx0, (m3 >= 0.0f) ? iz : 0.0f);
            // pixel 1: incremental along Y (YP1 = YP + DYC)
            float n0b = fmaf(g0.y, DYC, n0);
            float n1b = fmaf(g1.y, DYC, n1);
            float izb = fmaf(g2.y, DYC, iz);
            float n2b = (g0.w - n0b) - n1b;
            float m3b = fminf(fminf(n0b, n1b), n2b);
            mx1 = fmaxf(mx1, (m3b >= 0.0f) ? izb : 0.0f);
        }

        // depth = 1/max(iz): rcp is monotone-decreasing on positives, so
        // min over faces of 1/iz == 1/(max iz). One rcp per pixel per slice.
        if (h0 < HH && mx0 > 0.0f) {
            float depth = __builtin_amdgcn_rcpf(mx0);
            atomicMin((unsigned int*)&out[h0 * WW + w], __float_as_uint(depth));
            atomicMax((unsigned int*)&out[HH * WW + h0 * WW + w],
                      __float_as_uint(1.0f));
        }
        if (h1 < HH && mx1 > 0.0f) {
            float depth = __builtin_amdgcn_rcpf(mx1);
            atomicMin((unsigned int*)&out[h1 * WW + w], __float_as_uint(depth));
            atomicMax((unsigned int*)&out[HH * WW + h1 * WW + w],
                      __float_as_uint(1.0f));
        }
    }
}

extern "C" void kernel_launch(void* const* d_in, const int* in_sizes, int n_in,
                              void* d_out, int out_size, void* d_ws, size_t ws_size,
                              hipStream_t stream) {
    const float* verts = (const float*)d_in[0];
    const int*   faces = (const int*)d_in[1];
    const float* K     = (const float*)d_in[2];
    const float* R     = (const float*)d_in[3];
    const float* t     = (const float*)d_in[4];
    float* out = (float*)d_out;

    int M = in_sizes[1] / 3;   // 2048

    char* ws = (char*)d_ws;
    float4* bbox = (float4*)ws;                ws += (size_t)M * sizeof(float4);
    float4* G0   = (float4*)ws;                ws += (size_t)M * sizeof(float4);
    float4* G1   = (float4*)ws;                ws += (size_t)M * sizeof(float4);
    float2* G2   = (float2*)ws;                ws += (size_t)M * sizeof(float2);

    prep_kernel<<<(HH * WW + 255) / 256, 256, 0, stream>>>(
        verts, faces, K, R, t, bbox, G0, G1, G2, out, M);

    dim3 blk(16, 16);
    dim3 grd((WW + 15) / 16, (HH + 31) / 32, SPLIT);
    raster_kernel<<<grd, blk, 0, stream>>>(bbox, G0, G1, G2, out, M);
}

// Round 2
// 75.922 us; speedup vs baseline: 1.1822x; 1.0719x over previous
//
#include <hip/hip_runtime.h>

#define SS 304
#define HH 228
#define WW 304
#define FARV 100.0f
#define EPSV 1e-07f
#define SPLIT 8          // face-range slices (gridDim.z)
#define CH 256           // faces per slice == one staging chunk
// Each thread covers rows h and h+16 of a 32-row tile: YP(h+16) = YP(h) - 32/SS
#define DYC (-32.0f / (float)SS)

// per-vertex transform (contract off, IEEE divides — once per face, cheap)
__device__ __forceinline__ void xform_vertex(
    float u, float v, float d,
    float fx, float cx, float fy, float cy,
    float r00, float r01, float r02,
    float r10, float r11, float r12,
    float r20, float r21, float r22,
    float t0, float t1, float t2,
    float& xn, float& yn, float& z)
{
#pragma clang fp contract(off)
    float ki00 = 1.0f / fx;
    float ki02 = -(cx / fx);
    float ki11 = 1.0f / fy;
    float ki12 = -(cy / fy);
    float px = u * (float)WW;
    float py = v * (float)HH;
    float c0 = (ki00 * px + ki02) * d;
    float c1 = (ki11 * py + ki12) * d;
    float c2 = d;
    float e0 = ((r00*c0 + r01*c1) + r02*c2) + t0;
    float e1 = ((r10*c0 + r11*c1) + r12*c2) + t1;
    float e2 = ((r20*c0 + r21*c1) + r22*c2) + t2;
    z = e2;
    float zd = z + EPSV;
    float p0 = e0 / zd;
    float p1 = e1 / zd;
    float q0 = p0 * fx + cx;
    float q1 = p1 * fy + cy;
    float uu = q0 / (float)WW; uu = fminf(fmaxf(uu, 0.0f), 1.0f);
    float vv = q1 / (float)HH; vv = fminf(fmaxf(vv, 0.0f), 1.0f);
    xn = uu * (float)WW / (float)SS * 2.0f - 1.0f;
    yn = vv * (float)HH / (float)SS * 2.0f - 1.0f;
}

// ---- Kernel 1: out init + per-face vertex transform + plane precompute ----
// Per face we emit screen-space planes (sign-normalized so inside <=> >=0):
//   n0(X,Y) = A0*X + B0*Y + C0        (w0 numerator * sign(denom))
//   n1(X,Y) = A1*X + B1*Y + C1
//   n2      = |denom| - n0 - n1       (w2 numerator * sign(denom))
//   iz(X,Y) = E*X + F*Y + G           (interpolated 1/z — linear in X,Y)
__global__ __launch_bounds__(256) void prep_kernel(
    const float* __restrict__ verts,
    const int* __restrict__ faces,
    const float* __restrict__ Km,
    const float* __restrict__ Rm,
    const float* __restrict__ tm,
    float4* __restrict__ bboxArr,
    float4* __restrict__ G0arr,
    float4* __restrict__ G1arr,
    float2* __restrict__ G2arr,
    float* __restrict__ out, int M)
{
#pragma clang fp contract(off)
    int g = blockIdx.x * blockDim.x + threadIdx.x;
    if (g < HH * WW) {
        out[g] = FARV;
        out[HH * WW + g] = 0.0f;
    }
    if (g >= M) return;
    int m = g;
    int i0 = faces[3*m+0], i1 = faces[3*m+1], i2 = faces[3*m+2];
    float fx = Km[0], cx = Km[2], fy = Km[4], cy = Km[5];
    float r00 = Rm[0], r01 = Rm[1], r02 = Rm[2];
    float r10 = Rm[3], r11 = Rm[4], r12 = Rm[5];
    float r20 = Rm[6], r21 = Rm[7], r22 = Rm[8];
    float t0 = tm[0], t1 = tm[1], t2 = tm[2];

    float x0, y0, z0, x1, y1, z1, x2, y2, z2;
    xform_vertex(verts[3*i0+0], verts[3*i0+1], verts[3*i0+2], fx,cx,fy,cy,
                 r00,r01,r02,r10,r11,r12,r20,r21,r22,t0,t1,t2, x0,y0,z0);
    xform_vertex(verts[3*i1+0], verts[3*i1+1], verts[3*i1+2], fx,cx,fy,cy,
                 r00,r01,r02,r10,r11,r12,r20,r21,r22,t0,t1,t2, x1,y1,z1);
    xform_vertex(verts[3*i2+0], verts[3*i2+1], verts[3*i2+2], fx,cx,fy,cy,
                 r00,r01,r02,r10,r11,r12,r20,r21,r22,t0,t1,t2, x2,y2,z2);

    float A0 = y1 - y2;
    float B0 = x2 - x1;
    float A1 = y2 - y0;
    float B1 = x0 - x2;
    float dy02 = y0 - y2;
    float denom = A0 * B1 + B0 * dy02;
    bool ok = fabsf(denom) > 1e-10f;

    float xmin, xmax, ymin, ymax;
    if (ok) {
        xmin = fminf(x0, fminf(x1, x2)) - 1e-4f;
        xmax = fmaxf(x0, fmaxf(x1, x2)) + 1e-4f;
        ymin = fminf(y0, fminf(y1, y2)) - 1e-4f;
        ymax = fmaxf(y0, fmaxf(y1, y2)) + 1e-4f;
    } else {
        xmin = 1e30f; xmax = -1e30f; ymin = 1e30f; ymax = -1e30f;
    }
    bboxArr[m] = make_float4(xmin, xmax, ymin, ymax);

    float flip = (denom >= 0.0f) ? 1.0f : -1.0f;
    float sabs = fabsf(denom);
    float A0p = flip * A0, B0p = flip * B0;
    float C0p = -(A0p * x2 + B0p * y2);
    float A1p = flip * A1, B1p = flip * B1;
    float C1p = -(A1p * x2 + B1p * y2);
    float rz0 = 1.0f / z0, rz1 = 1.0f / z1, rz2 = 1.0f / z2;
    float D0 = rz0 / sabs, D1 = rz1 / sabs, D2 = rz2 / sabs;
    // iz = n0*D0 + n1*D1 + (sabs - n0 - n1)*D2  ->  plane E,F,G
    float d02 = D0 - D2, d12 = D1 - D2;
    float E = A0p * d02 + A1p * d12;
    float F = B0p * d02 + B1p * d12;
    float G = (C0p * d02 + C1p * d12) + sabs * D2;

    G0arr[m] = make_float4(A0p, B0p, C0p, sabs);
    G1arr[m] = make_float4(A1p, B1p, C1p, G);
    G2arr[m] = make_float2(E, F);
}

// ---- Kernel 2: rasterize (LDS-staged, face-sliced, branchless core) ----
// v3: staging cull upgraded from bbox-only to exact SAT (bbox axes + the 3
// edge half-planes evaluated at tile corners). For random-vertex triangles
// the bbox pass rate is ~33% while true tile-intersection is ~14% — this
// cuts the inner-loop trip count ~2.4x at the cost of ~12 VALU per face in
// the (fully parallel, once-per-block) staging phase.
__global__ __launch_bounds__(256) void raster_kernel(
    const float4* __restrict__ bboxArr,
    const float4* __restrict__ G0arr,
    const float4* __restrict__ G1arr,
    const float2* __restrict__ G2arr,
    float* __restrict__ out, int M)
{
    __shared__ float4 sG0[CH];
    __shared__ float4 sG1[CH];
    __shared__ float2 sG2[CH];
    __shared__ int sCount;

    int tx = threadIdx.x, ty = threadIdx.y;
    int tid = ty * 16 + tx;
    int w  = blockIdx.x * 16 + tx;
    int h0 = blockIdx.y * 32 + ty;        // rows h0 and h0+16
    int h1 = h0 + 16;

    int wlo = blockIdx.x * 16;
    int whi = min(wlo + 15, WW - 1);
    int hlo = blockIdx.y * 32;
    int hhi = min(hlo + 31, HH - 1);
    float txlo = ((float)(2*wlo + 1 - SS)) / (float)SS;
    float txhi = ((float)(2*whi + 1 - SS)) / (float)SS;
    float tylo = ((float)(2*(SS-1-hhi) + 1 - SS)) / (float)SS;
    float tyhi = ((float)(2*(SS-1-hlo) + 1 - SS)) / (float)SS;

    if (tid == 0) sCount = 0;
    __syncthreads();

    {
        int m = blockIdx.z * CH + tid;   // M == SPLIT*CH == 2048
        if (m < M) {
            float4 rb = bboxArr[m];
            bool pass = !(rb.x > txhi || rb.y < txlo || rb.z > tyhi || rb.w < tylo);
            if (pass) {
                float4 g0 = G0arr[m];
                float4 g1 = G1arr[m];
                // SAT edge tests: max of each (sign-normalized) edge plane
                // over the tile corner rectangle; all-negative => the tile
                // lies entirely outside that edge => no pixel can be inside.
                // Slack 1e-5 >> fp32 rounding of the per-pixel fmaf eval.
                float e0 = fmaxf(g0.x * txlo, g0.x * txhi)
                         + fmaxf(g0.y * tylo, g0.y * tyhi) + g0.z;
                float e1 = fmaxf(g1.x * txlo, g1.x * txhi)
                         + fmaxf(g1.y * tylo, g1.y * tyhi) + g1.z;
                float A2 = -(g0.x + g1.x);
                float B2 = -(g0.y + g1.y);
                float C2 = g0.w - g0.z - g1.z;
                float e2 = fmaxf(A2 * txlo, A2 * txhi)
                         + fmaxf(B2 * tylo, B2 * tyhi) + C2;
                if (e0 >= -1e-5f && e1 >= -1e-5f && e2 >= -1e-5f) {
                    int i = atomicAdd(&sCount, 1);
                    sG0[i] = g0;
                    sG1[i] = g1;
                    sG2[i] = G2arr[m];
                }
            }
        }
    }
    __syncthreads();
    int cnt = sCount;

    {
        int irow = SS - 1 - h0;
        float XP = ((float)(2*w    + 1 - SS)) / (float)SS;
        float YP = ((float)(2*irow + 1 - SS)) / (float)SS;

        float mx0 = 0.0f;   // running max of interpolated 1/z, pixel (h0,w)
        float mx1 = 0.0f;   // pixel (h1,w)

        for (int k = 0; k < cnt; ++k) {
            float4 g0 = sG0[k];
            float4 g1 = sG1[k];
            float2 g2 = sG2[k];
            // pixel 0: full plane eval
            float n0 = fmaf(g0.x, XP, fmaf(g0.y, YP, g0.z));
            float n1 = fmaf(g1.x, XP, fmaf(g1.y, YP, g1.z));
            float iz = fmaf(g2.x, XP, fmaf(g2.y, YP, g1.w));
            float n2 = (g0.w - n0) - n1;
            float m3 = fminf(fminf(n0, n1), n2);
            mx0 = fmaxf(mx0, (m3 >= 0.0f) ? iz : 0.0f);
            // pixel 1: incremental along Y (YP1 = YP + DYC)
            float n0b = fmaf(g0.y, DYC, n0);
            float n1b = fmaf(g1.y, DYC, n1);
            float izb = fmaf(g2.y, DYC, iz);
            float n2b = (g0.w - n0b) - n1b;
            float m3b = fminf(fminf(n0b, n1b), n2b);
            mx1 = fmaxf(mx1, (m3b >= 0.0f) ? izb : 0.0f);
        }

        // depth = 1/max(iz): rcp is monotone-decreasing on positives, so
        // min over faces of 1/iz == 1/(max iz). One rcp per pixel per slice.
        if (h0 < HH && mx0 > 0.0f) {
            float depth = __builtin_amdgcn_rcpf(mx0);
            atomicMin((unsigned int*)&out[h0 * WW + w], __float_as_uint(depth));
            atomicMax((unsigned int*)&out[HH * WW + h0 * WW + w],
                      __float_as_uint(1.0f));
        }
        if (h1 < HH && mx1 > 0.0f) {
            float depth = __builtin_amdgcn_rcpf(mx1);
            atomicMin((unsigned int*)&out[h1 * WW + w], __float_as_uint(depth));
            atomicMax((unsigned int*)&out[HH * WW + h1 * WW + w],
                      __float_as_uint(1.0f));
        }
    }
}

extern "C" void kernel_launch(void* const* d_in, const int* in_sizes, int n_in,
                              void* d_out, int out_size, void* d_ws, size_t ws_size,
                              hipStream_t stream) {
    const float* verts = (const float*)d_in[0];
    const int*   faces = (const int*)d_in[1];
    const float* K     = (const float*)d_in[2];
    const float* R     = (const float*)d_in[3];
    const float* t     = (const float*)d_in[4];
    float* out = (float*)d_out;

    int M = in_sizes[1] / 3;   // 2048

    char* ws = (char*)d_ws;
    float4* bbox = (float4*)ws;                ws += (size_t)M * sizeof(float4);
    float4* G0   = (float4*)ws;                ws += (size_t)M * sizeof(float4);
    float4* G1   = (float4*)ws;                ws += (size_t)M * sizeof(float4);
    float2* G2   = (float2*)ws;                ws += (size_t)M * sizeof(float2);

    prep_kernel<<<(HH * WW + 255) / 256, 256, 0, stream>>>(
        verts, faces, K, R, t, bbox, G0, G1, G2, out, M);

    dim3 blk(16, 16);
    dim3 grd((WW + 15) / 16, (HH + 31) / 32, SPLIT);
    raster_kernel<<<grd, blk, 0, stream>>>(bbox, G0, G1, G2, out, M);
}